// Round 2
// baseline (213.103 us; speedup 1.0000x reference)
//
#include <hip/hip_runtime.h>

// Dice loss (hard, exclude background=class 0), B=2, C=8, S=128^3.
// pred: (B, C, 128,128,128) fp32 ; ref: (B, 1, 128,128,128) int32 ; out: scalar fp32.

#define S_VOX (128 * 128 * 128)   // 2,097,152 voxels per (b, c) slice
#define S4    (S_VOX / 4)         // 524,288 float4 groups per slice
#define NC    8                   // channels

// ws layout (int): per batch b: ws[b*24 + t*8 + c], t: 0=inter 1=pred 2=ref, c=class 0..7
#define WS_INTS (2 * 3 * NC)

#define BYTE_MASK 0x00FF00FF00FF00FFULL

// Per-component: argmax over 8 channels (strict >, ascending order = jnp.argmax
// first-max semantics), then one packed-byte increment per counter.
#define PROC_COMP(C)                                                     \
    {                                                                    \
        float bv = a0.C; int bi = 0;                                     \
        if (a1.C > bv) { bv = a1.C; bi = 1; }                            \
        if (a2.C > bv) { bv = a2.C; bi = 2; }                            \
        if (a3.C > bv) { bv = a3.C; bi = 3; }                            \
        if (a4.C > bv) { bv = a4.C; bi = 4; }                            \
        if (a5.C > bv) { bv = a5.C; bi = 5; }                            \
        if (a6.C > bv) { bv = a6.C; bi = 6; }                            \
        if (a7.C > bv) { bv = a7.C; bi = 7; }                            \
        const int rr = r.C;                                              \
        const unsigned long long pa = 1ULL << (bi * 8);                  \
        pcnt += pa;                                                      \
        rcnt += 1ULL << (rr * 8);                                        \
        icnt += (bi == rr) ? pa : 0ULL;                                  \
    }

__global__ __launch_bounds__(256) void dice_count_kernel(
    const float4* __restrict__ pred4, const int4* __restrict__ ref4,
    int* __restrict__ ws)
{
    const int b = blockIdx.y;
    unsigned long long icnt = 0, pcnt = 0, rcnt = 0;   // 8 byte-lanes = 8 classes

    const int tid      = blockIdx.x * blockDim.x + threadIdx.x;
    const int nthreads = gridDim.x * blockDim.x;       // 131072 -> 4 iters, 16 vox/thread
    const long long predBase = (long long)b * NC * S4;
    const long long refBase  = (long long)b * S4;

    for (int g = tid; g < S4; g += nthreads) {
        const float4 a0 = pred4[predBase + (long long)0 * S4 + g];
        const float4 a1 = pred4[predBase + (long long)1 * S4 + g];
        const float4 a2 = pred4[predBase + (long long)2 * S4 + g];
        const float4 a3 = pred4[predBase + (long long)3 * S4 + g];
        const float4 a4 = pred4[predBase + (long long)4 * S4 + g];
        const float4 a5 = pred4[predBase + (long long)5 * S4 + g];
        const float4 a6 = pred4[predBase + (long long)6 * S4 + g];
        const float4 a7 = pred4[predBase + (long long)7 * S4 + g];
        const int4   r  = ref4[refBase + g];
        PROC_COMP(x)
        PROC_COMP(y)
        PROC_COMP(z)
        PROC_COMP(w)
    }

    // Split packed bytes into 16-bit lanes (even classes in lo, odd in hi).
    // Word order per counter t: [lo0 (cls 0,2), lo1 (cls 4,6), hi0 (cls 1,3), hi1 (cls 5,7)]
    unsigned w[12];
    {
        const unsigned long long li = icnt & BYTE_MASK, hi = (icnt >> 8) & BYTE_MASK;
        const unsigned long long lp = pcnt & BYTE_MASK, hp = (pcnt >> 8) & BYTE_MASK;
        const unsigned long long lr = rcnt & BYTE_MASK, hr = (rcnt >> 8) & BYTE_MASK;
        w[0] = (unsigned)li; w[1] = (unsigned)(li >> 32); w[2]  = (unsigned)hi; w[3]  = (unsigned)(hi >> 32);
        w[4] = (unsigned)lp; w[5] = (unsigned)(lp >> 32); w[6]  = (unsigned)hp; w[7]  = (unsigned)(hp >> 32);
        w[8] = (unsigned)lr; w[9] = (unsigned)(lr >> 32); w[10] = (unsigned)hr; w[11] = (unsigned)(hr >> 32);
    }

    // Wave (64-lane) shuffle reduction of 12 packed words.
    // 16-bit lane sums <= 64 lanes * 16 vox = 1024: no overflow.
#pragma unroll
    for (int j = 0; j < 12; ++j) {
#pragma unroll
        for (int off = 32; off > 0; off >>= 1)
            w[j] += __shfl_down(w[j], off, 64);
    }

    __shared__ unsigned sh[12];
    if (threadIdx.x < 12) sh[threadIdx.x] = 0;
    __syncthreads();

    if ((threadIdx.x & 63) == 0) {
        // Block lane sums <= 4 waves * 1024 = 4096: still < 65536, no overflow.
#pragma unroll
        for (int j = 0; j < 12; ++j) atomicAdd(&sh[j], w[j]);
    }
    __syncthreads();

    if (threadIdx.x < 12) {
        const int j = threadIdx.x;
        const int t = j >> 2;          // counter: 0=inter 1=pred 2=ref
        const int q = j & 3;
        const int c0tab[4] = {0, 4, 1, 5};
        const int c0 = c0tab[q];       // classes (c0, c0+2) in (lo16, hi16)
        const unsigned v = sh[j];
        atomicAdd(&ws[b * 24 + t * 8 + c0],     (int)(v & 0xFFFFu));
        atomicAdd(&ws[b * 24 + t * 8 + c0 + 2], (int)(v >> 16));
    }
}

__global__ void dice_finalize_kernel(const int* __restrict__ ws,
                                     float* __restrict__ out)
{
    if (blockIdx.x == 0 && threadIdx.x == 0) {
        float total = 0.0f;
#pragma unroll
        for (int b = 0; b < 2; ++b) {
            const int* w = ws + b * 24;
            float sumd = 0.0f, sumw = 0.0f;
#pragma unroll
            for (int c = 1; c < NC; ++c) {
                const int I = w[0 * 8 + c];
                const int P = w[1 * 8 + c];
                const int R = w[2 * 8 + c];
                if (R > 0) {
                    sumw += 1.0f;
                    sumd += 2.0f * (float)I / (float)(P + R);
                }
            }
            total += sumd / sumw;   // matches reference (NaN if no fg classes)
        }
        out[0] = 0.5f * total;
    }
}

extern "C" void kernel_launch(void* const* d_in, const int* in_sizes, int n_in,
                              void* d_out, int out_size, void* d_ws, size_t ws_size,
                              hipStream_t stream) {
    const float* pred = (const float*)d_in[0];
    const int*   ref  = (const int*)d_in[1];
    float*       out  = (float*)d_out;
    int*         ws   = (int*)d_ws;

    // ws is re-poisoned to 0xAA before every timed launch -> zero the 48 ints we use.
    hipMemsetAsync(ws, 0, WS_INTS * sizeof(int), stream);

    // 1024 blocks (4/CU, 16 waves/CU) x 256 threads; grid.y = batch.
    dim3 grid(512, 2, 1);
    dim3 block(256, 1, 1);
    dice_count_kernel<<<grid, block, 0, stream>>>(
        (const float4*)pred, (const int4*)ref, ws);
    dice_finalize_kernel<<<1, 64, 0, stream>>>(ws, out);
}